// Round 1
// baseline (44.494 us; speedup 1.0000x reference)
//
#include <hip/hip_runtime.h>

// SpectralConv2D: out[f,o,c] = relu( sum_kk SM[f,kk] * (Lin[col(o,kk)] - Lout[o]) * x[col(o,kk), c] )
// F=128, O=62*62=3844, C=128, KK=9.  Output (F, 62, 62, C) fp32 = 252 MB -> write-bound.

#define FILTERS 128
#define KK 9
#define HH 64
#define WW 64
#define C_IN 128
#define OUT1 62
#define OUT2 62
#define O_TOTAL (OUT1 * OUT2)   // 3844

#define O_PER_BLOCK 8           // 8 groups of 32 lanes (c-quads) per 256-thread block
#define F_PER_BLOCK 32          // each block computes 32 filters for its o-tile

__global__ __launch_bounds__(256) void spectral_conv2d_kernel(
    const float* __restrict__ x,     // (H*W, C) row-major
    const float* __restrict__ SM,    // (F, 9)
    const float* __restrict__ Lin,   // (H*W,)
    const float* __restrict__ Lout,  // (O,)
    float* __restrict__ out)         // (F, O, C)
{
    const int tid = threadIdx.x;
    const int g   = tid >> 5;        // 0..7 : which o within the block tile
    const int cl  = tid & 31;        // 0..31: which c-quad (c = cl*4 .. cl*4+3)

    const int o  = blockIdx.y * O_PER_BLOCK + g;
    const int f0 = blockIdx.x * F_PER_BLOCK;
    if (o >= O_TOTAL) return;

    const int r  = o / OUT2;
    const int cc = o - r * OUT2;
    const float lout = Lout[o];

    // Load the 9 patch c-quads once, pre-scaled by lam[o,kk].
    float4 p[KK];
#pragma unroll
    for (int kk = 0; kk < KK; ++kk) {
        const int b = kk / 3;
        const int j = kk - b * 3;
        const int col = (r + b) * WW + (cc + j);
        const float lam = Lin[col] - lout;
        const float4 v = *reinterpret_cast<const float4*>(x + (size_t)col * C_IN + (size_t)cl * 4);
        p[kk] = make_float4(lam * v.x, lam * v.y, lam * v.z, lam * v.w);
    }

    size_t out_idx = (size_t)f0 * O_TOTAL * C_IN + (size_t)o * C_IN + (size_t)cl * 4;
    const size_t f_stride = (size_t)O_TOTAL * C_IN;

#pragma unroll 4
    for (int fi = 0; fi < F_PER_BLOCK; ++fi) {
        const int f = f0 + fi;                 // block-uniform -> s_load for SM
        float4 acc = make_float4(0.f, 0.f, 0.f, 0.f);
#pragma unroll
        for (int kk = 0; kk < KK; ++kk) {
            const float w = SM[f * KK + kk];
            acc.x = fmaf(w, p[kk].x, acc.x);
            acc.y = fmaf(w, p[kk].y, acc.y);
            acc.z = fmaf(w, p[kk].z, acc.z);
            acc.w = fmaf(w, p[kk].w, acc.w);
        }
        acc.x = fmaxf(acc.x, 0.f);
        acc.y = fmaxf(acc.y, 0.f);
        acc.z = fmaxf(acc.z, 0.f);
        acc.w = fmaxf(acc.w, 0.f);
        *reinterpret_cast<float4*>(out + out_idx) = acc;
        out_idx += f_stride;
    }
}

extern "C" void kernel_launch(void* const* d_in, const int* in_sizes, int n_in,
                              void* d_out, int out_size, void* d_ws, size_t ws_size,
                              hipStream_t stream) {
    const float* x    = (const float*)d_in[0];  // (1, 64, 64, 128)
    const float* SM   = (const float*)d_in[1];  // (128, 9)
    const float* Lin  = (const float*)d_in[2];  // (1, 4096)
    const float* Lout = (const float*)d_in[3];  // (3844, 1)
    float* out = (float*)d_out;                 // (128, 62, 62, 128)

    dim3 block(256, 1, 1);
    dim3 grid(FILTERS / F_PER_BLOCK, (O_TOTAL + O_PER_BLOCK - 1) / O_PER_BLOCK, 1);
    spectral_conv2d_kernel<<<grid, block, 0, stream>>>(x, SM, Lin, Lout, out);
}